// Round 2
// baseline (1570.421 us; speedup 1.0000x reference)
//
#include <hip/hip_runtime.h>
#include <cstdint>
#include <cstddef>

// Problem constants (match reference)
#define NN 100000   // nodes
#define NE 1600000  // edges
#define HD 64       // hidden width
#define NC 16       // classes

// ---------------------------------------------------------------------------
// Workspace layout (bytes) — total 51,600,128 B (~51.6 MB):
//   dinv : [0, 400128)          N floats (deg -> dinv in place)
//   A    : 400128               N*64 floats  (h0 -> h2 -> h3)
//   B    : 400128 + NB          N*64 floats  (agg1 -> agg2)
// ---------------------------------------------------------------------------

__global__ __launch_bounds__(256) void k_deg_init(float* __restrict__ deg) {
    int i = blockIdx.x * 256 + threadIdx.x;
    if (i < NN) deg[i] = 1.0f;  // self-loop weight
}

__global__ __launch_bounds__(256) void k_deg_accum(const int* __restrict__ dst,
                                                   const float* __restrict__ ew,
                                                   float* __restrict__ deg) {
    int e = blockIdx.x * 256 + threadIdx.x;
    if (e < NE) atomicAdd(&deg[dst[e]], ew[e]);
}

__global__ __launch_bounds__(256) void k_dinv(float* __restrict__ deg) {
    int i = blockIdx.x * 256 + threadIdx.x;
    if (i < NN) {
        float d = deg[i];
        deg[i] = d > 0.0f ? rsqrtf(d) : 0.0f;
    }
}

#define FMA16(xv)                                                      \
    acc[0] = fmaf(xv, w0.x, acc[0]);  acc[1] = fmaf(xv, w0.y, acc[1]); \
    acc[2] = fmaf(xv, w0.z, acc[2]);  acc[3] = fmaf(xv, w0.w, acc[3]); \
    acc[4] = fmaf(xv, w1.x, acc[4]);  acc[5] = fmaf(xv, w1.y, acc[5]); \
    acc[6] = fmaf(xv, w1.z, acc[6]);  acc[7] = fmaf(xv, w1.w, acc[7]); \
    acc[8] = fmaf(xv, w2.x, acc[8]);  acc[9] = fmaf(xv, w2.y, acc[9]); \
    acc[10] = fmaf(xv, w2.z, acc[10]); acc[11] = fmaf(xv, w2.w, acc[11]); \
    acc[12] = fmaf(xv, w3.x, acc[12]); acc[13] = fmaf(xv, w3.y, acc[13]); \
    acc[14] = fmaf(xv, w3.z, acc[14]); acc[15] = fmaf(xv, w3.w, acc[15]);

// h0 = x @ W1 ; agg1 = h0 * dinv^2  (self-loop init; x is an input, no alias)
// block: 256 threads -> 64 rows x (4 col-groups of 16). grid = ceil(N/64).
__global__ __launch_bounds__(256) void k_gemm1(const float* __restrict__ x,
                                               const float* __restrict__ W1,
                                               const float* __restrict__ dinv,
                                               float* __restrict__ h0,
                                               float* __restrict__ agg1) {
    int tid = threadIdx.x;
    int row = blockIdx.x * 64 + (tid >> 2);
    int cg  = (tid & 3) * 16;
    if (row >= NN) return;
    float acc[16];
#pragma unroll
    for (int c = 0; c < 16; ++c) acc[c] = 0.0f;
    const float* xr = x + (size_t)row * 256;
#pragma unroll 4
    for (int k = 0; k < 256; ++k) {
        float xv = xr[k];
        const float4* wp = (const float4*)(W1 + (size_t)k * HD + cg);
        float4 w0 = wp[0], w1 = wp[1], w2 = wp[2], w3 = wp[3];
        FMA16(xv)
    }
    float di = dinv[row];
    float d2 = di * di;
    float4* hp = (float4*)(h0 + (size_t)row * HD + cg);
    float4* ap = (float4*)(agg1 + (size_t)row * HD + cg);
#pragma unroll
    for (int q = 0; q < 4; ++q) {
        float4 v = make_float4(acc[q * 4], acc[q * 4 + 1], acc[q * 4 + 2], acc[q * 4 + 3]);
        hp[q] = v;
        ap[q] = make_float4(v.x * d2, v.y * d2, v.z * d2, v.w * d2);
    }
}

// outA = (relu(in + bin)) @ W [+ optional relu(.+bout)]. K=64 fixed.
// No in-place aliasing: reads `in` (buffer B), writes outA (buffer A).
template <bool BIASRELU>
__global__ __launch_bounds__(256) void k_gemm64(const float* __restrict__ in,
                                                const float* __restrict__ bin,
                                                const float* __restrict__ W,
                                                const float* __restrict__ bout,
                                                float* __restrict__ outA) {
    int tid = threadIdx.x;
    int row = blockIdx.x * 64 + (tid >> 2);
    int cg  = (tid & 3) * 16;
    if (row >= NN) return;
    float acc[16];
#pragma unroll
    for (int c = 0; c < 16; ++c) acc[c] = 0.0f;
    const float* ir = in + (size_t)row * HD;
#pragma unroll 4
    for (int k = 0; k < 64; ++k) {
        float hv = fmaxf(ir[k] + bin[k], 0.0f);  // relu(agg + b) feeding this layer
        const float4* wp = (const float4*)(W + (size_t)k * HD + cg);
        float4 w0 = wp[0], w1 = wp[1], w2 = wp[2], w3 = wp[3];
        FMA16(hv)
    }
    float4* ha = (float4*)(outA + (size_t)row * HD + cg);
    if (BIASRELU) {
#pragma unroll
        for (int q = 0; q < 4; ++q) {
            float4 v;
            v.x = fmaxf(acc[q * 4 + 0] + bout[cg + q * 4 + 0], 0.0f);
            v.y = fmaxf(acc[q * 4 + 1] + bout[cg + q * 4 + 1], 0.0f);
            v.z = fmaxf(acc[q * 4 + 2] + bout[cg + q * 4 + 2], 0.0f);
            v.w = fmaxf(acc[q * 4 + 3] + bout[cg + q * 4 + 3], 0.0f);
            ha[q] = v;
        }
    } else {
#pragma unroll
        for (int q = 0; q < 4; ++q)
            ha[q] = make_float4(acc[q * 4], acc[q * 4 + 1], acc[q * 4 + 2], acc[q * 4 + 3]);
    }
}

// agg[i] = h[i] * dinv[i/64]^2  (self-loop init; reads A, writes B — no alias)
__global__ __launch_bounds__(256) void k_selfloop(const float* __restrict__ h,
                                                  const float* __restrict__ dinv,
                                                  float* __restrict__ agg) {
    int i = blockIdx.x * 256 + threadIdx.x;  // float4 index, N*64/4 total
    if (i >= NN * (HD / 4)) return;
    int row = i / (HD / 4);
    float di = dinv[row];
    float d2 = di * di;
    float4 v = ((const float4*)h)[i];
    ((float4*)agg)[i] = make_float4(v.x * d2, v.y * d2, v.z * d2, v.w * d2);
}

// One wave per edge, lane = feature. agg[dst] += h[src] * dinv[s]*w*dinv[d]
__global__ __launch_bounds__(256) void k_scatter(const int* __restrict__ src,
                                                 const int* __restrict__ dst,
                                                 const float* __restrict__ ew,
                                                 const float* __restrict__ dinv,
                                                 const float* __restrict__ h,
                                                 float* __restrict__ agg) {
    int e = blockIdx.x * 4 + (threadIdx.x >> 6);
    int lane = threadIdx.x & 63;
    if (e >= NE) return;
    int s = src[e];
    int d = dst[e];
    float nrm = dinv[s] * ew[e] * dinv[d];
    float v = h[(size_t)s * HD + lane] * nrm;
    atomicAdd(&agg[(size_t)d * HD + lane], v);
}

// Per-thread node: logits = h3 @ Wm2 + bm2, softmax, store 16 floats.
__global__ __launch_bounds__(256) void k_out(const float* __restrict__ h3,
                                             const float* __restrict__ Wm2,
                                             const float* __restrict__ bm2,
                                             float* __restrict__ out) {
    int i = blockIdx.x * 256 + threadIdx.x;
    if (i >= NN) return;
    float acc[16];
#pragma unroll
    for (int c = 0; c < 16; ++c) acc[c] = bm2[c];
    const float* hr = h3 + (size_t)i * HD;
#pragma unroll 4
    for (int k = 0; k < 64; ++k) {
        float hv = hr[k];
        const float4* wp = (const float4*)(Wm2 + k * NC);
        float4 w0 = wp[0], w1 = wp[1], w2 = wp[2], w3 = wp[3];
        FMA16(hv)
    }
    float m = acc[0];
#pragma unroll
    for (int c = 1; c < 16; ++c) m = fmaxf(m, acc[c]);
    float ssum = 0.0f;
#pragma unroll
    for (int c = 0; c < 16; ++c) {
        acc[c] = expf(acc[c] - m);
        ssum += acc[c];
    }
    float inv = 1.0f / ssum;
    float4* op = (float4*)(out + (size_t)i * NC);
#pragma unroll
    for (int q = 0; q < 4; ++q)
        op[q] = make_float4(acc[q * 4] * inv, acc[q * 4 + 1] * inv,
                            acc[q * 4 + 2] * inv, acc[q * 4 + 3] * inv);
}

extern "C" void kernel_launch(void* const* d_in, const int* in_sizes, int n_in,
                              void* d_out, int out_size, void* d_ws, size_t ws_size,
                              hipStream_t stream) {
    const float* x   = (const float*)d_in[0];
    const int*   ei  = (const int*)d_in[1];   // (2, E): [0,E)=src, [E,2E)=dst
    const float* ew  = (const float*)d_in[2];
    const float* W1  = (const float*)d_in[3];
    const float* b1  = (const float*)d_in[4];
    const float* W2  = (const float*)d_in[5];
    const float* b2  = (const float*)d_in[6];
    const float* Wm1 = (const float*)d_in[7];
    const float* bm1 = (const float*)d_in[8];
    const float* Wm2 = (const float*)d_in[9];
    const float* bm2 = (const float*)d_in[10];
    float* out = (float*)d_out;

    char* base = (char*)d_ws;
    const size_t NB = (size_t)NN * HD * sizeof(float);  // 25,600,000 B
    float* dinv = (float*)base;
    float* A    = (float*)(base + 400128);       // h0 -> h2 -> h3
    float* B    = (float*)(base + 400128 + NB);  // agg1 -> agg2

    const int* src = ei;
    const int* dst = ei + NE;

    // degree -> dinv
    k_deg_init<<<dim3((NN + 255) / 256), dim3(256), 0, stream>>>(dinv);
    k_deg_accum<<<dim3(NE / 256), dim3(256), 0, stream>>>(dst, ew, dinv);
    k_dinv<<<dim3((NN + 255) / 256), dim3(256), 0, stream>>>(dinv);

    // layer 1: A = x@W1 ; B = A*dinv^2 (self-loop init) ; scatter edges A->B
    k_gemm1<<<dim3((NN + 63) / 64), dim3(256), 0, stream>>>(x, W1, dinv, A, B);
    k_scatter<<<dim3(NE / 4), dim3(256), 0, stream>>>(src, dst, ew, dinv, A, B);

    // layer 2: A = relu(B+b1)@W2 ; B = A*dinv^2 ; scatter A->B
    k_gemm64<false><<<dim3((NN + 63) / 64), dim3(256), 0, stream>>>(B, b1, W2, nullptr, A);
    k_selfloop<<<dim3((NN * (HD / 4) + 255) / 256), dim3(256), 0, stream>>>(A, dinv, B);
    k_scatter<<<dim3(NE / 4), dim3(256), 0, stream>>>(src, dst, ew, dinv, A, B);

    // MLP head: A = relu(relu(B+b2)@Wm1 + bm1) ; logits+softmax
    k_gemm64<true><<<dim3((NN + 63) / 64), dim3(256), 0, stream>>>(B, b2, Wm1, bm1, A);
    k_out<<<dim3((NN + 255) / 256), dim3(256), 0, stream>>>(A, Wm2, bm2, out);
}

// Round 3
// 1134.267 us; speedup vs baseline: 1.3845x; 1.3845x over previous
//
#include <hip/hip_runtime.h>
#include <cstdint>
#include <cstddef>

// Problem constants (match reference)
#define NN 100000   // nodes
#define NE 1600000  // edges
#define IN_F 256    // input feats
#define HD 64       // hidden width
#define NC 16       // classes

// ---------------------------------------------------------------------------
// Workspace layout (bytes) — total 51,600,128 B (~51.6 MB):
//   dinv : [0, 400128)          N floats (deg -> dinv in place)
//   A    : 400128               N*64 floats  (h0 -> h2 -> h3)
//   B    : 400128 + NB          N*64 floats  (agg1 -> agg2)
// ---------------------------------------------------------------------------

__global__ __launch_bounds__(256) void k_deg_init(float* __restrict__ deg) {
    int i = blockIdx.x * 256 + threadIdx.x;
    if (i < NN) deg[i] = 1.0f;  // self-loop weight
}

__global__ __launch_bounds__(256) void k_deg_accum(const int* __restrict__ dst,
                                                   const float* __restrict__ ew,
                                                   float* __restrict__ deg) {
    int e = blockIdx.x * 256 + threadIdx.x;
    if (e < NE) atomicAdd(&deg[dst[e]], ew[e]);
}

__global__ __launch_bounds__(256) void k_dinv(float* __restrict__ deg) {
    int i = blockIdx.x * 256 + threadIdx.x;
    if (i < NN) {
        float d = deg[i];
        deg[i] = d > 0.0f ? rsqrtf(d) : 0.0f;
    }
}

// ---------------------------------------------------------------------------
// h0 = x @ W1 (100000x256 @ 256x64); agg1 = h0 * dinv^2 (self-loop init).
// Block: 256 threads = 64 row-threads x 4 col-groups. Tile: 256 rows.
// Each thread: 4 rows x 16 cols = 64 accumulators. W1 staged in LDS in
// K=64 chunks (16 KB). Per k-step: 4 ds_read_b128 + 64 FMA -> VALU-bound.
// ---------------------------------------------------------------------------
__global__ __launch_bounds__(256, 4) void k_gemm1(const float* __restrict__ x,
                                                  const float* __restrict__ W1,
                                                  const float* __restrict__ dinv,
                                                  float* __restrict__ h0,
                                                  float* __restrict__ agg1) {
    __shared__ float sW[64 * HD];  // 16 KB chunk of W1
    int tid = threadIdx.x;
    int rt  = tid >> 2;           // 0..63
    int cg  = (tid & 3) * 16;     // 0,16,32,48
    int base = blockIdx.x * 256;
    int rowc[4];
    bool rv[4];
#pragma unroll
    for (int r = 0; r < 4; ++r) {
        int row = base + rt + 64 * r;
        rv[r] = row < NN;
        rowc[r] = rv[r] ? row : (NN - 1);
    }
    float acc[4][16];
#pragma unroll
    for (int r = 0; r < 4; ++r)
#pragma unroll
        for (int c = 0; c < 16; ++c) acc[r][c] = 0.0f;

    for (int kc = 0; kc < IN_F; kc += 64) {
        __syncthreads();  // protect sW from overwrite while still being read
        {   // stage 64x64 chunk = 1024 float4, coalesced
            const float4* wsrc = (const float4*)(W1 + (size_t)kc * HD);
            float4* wdst = (float4*)sW;
#pragma unroll
            for (int q = 0; q < 4; ++q) wdst[q * 256 + tid] = wsrc[q * 256 + tid];
        }
        __syncthreads();
        for (int k4 = 0; k4 < 16; ++k4) {
            float xs[4][4];
#pragma unroll
            for (int r = 0; r < 4; ++r)
                *(float4*)xs[r] = *(const float4*)(x + (size_t)rowc[r] * IN_F + kc + k4 * 4);
#pragma unroll
            for (int j = 0; j < 4; ++j) {
                float wv[16];
                const float4* wr4 = (const float4*)(sW + (k4 * 4 + j) * HD + cg);
#pragma unroll
                for (int q = 0; q < 4; ++q) ((float4*)wv)[q] = wr4[q];
#pragma unroll
                for (int r = 0; r < 4; ++r) {
                    float xj = xs[r][j];
#pragma unroll
                    for (int c = 0; c < 16; ++c) acc[r][c] = fmaf(xj, wv[c], acc[r][c]);
                }
            }
        }
    }
#pragma unroll
    for (int r = 0; r < 4; ++r) {
        if (!rv[r]) continue;
        float di = dinv[rowc[r]];
        float d2 = di * di;
        float4* hp = (float4*)(h0 + (size_t)rowc[r] * HD + cg);
        float4* ap = (float4*)(agg1 + (size_t)rowc[r] * HD + cg);
#pragma unroll
        for (int q = 0; q < 4; ++q) {
            float4 v = make_float4(acc[r][q * 4], acc[r][q * 4 + 1],
                                   acc[r][q * 4 + 2], acc[r][q * 4 + 3]);
            hp[q] = v;
            ap[q] = make_float4(v.x * d2, v.y * d2, v.z * d2, v.w * d2);
        }
    }
}

// ---------------------------------------------------------------------------
// outA = relu(in + bin) @ W  [K=64], with optional epilogues:
//   BIASRELU: outA = relu(acc + bout)
//   SELFLOOP: also outB = acc * dinv^2. outB may alias `in` (in-place):
//             a block only reads its own row tile, and we __syncthreads()
//             after the k-loop so all reads complete before stores.
// ---------------------------------------------------------------------------
template <bool BIASRELU, bool SELFLOOP>
__global__ __launch_bounds__(256, 4) void k_gemm64(const float* __restrict__ in,
                                                   const float* __restrict__ bin,
                                                   const float* __restrict__ W,
                                                   const float* __restrict__ bout,
                                                   const float* __restrict__ dinv,
                                                   float* __restrict__ outA,
                                                   float* __restrict__ outB) {
    __shared__ float sW[HD * HD];  // 16 KB
    __shared__ float sBin[HD];
    int tid = threadIdx.x;
    int rt  = tid >> 2;
    int cg  = (tid & 3) * 16;
    int base = blockIdx.x * 256;
    int rowc[4];
    bool rv[4];
#pragma unroll
    for (int r = 0; r < 4; ++r) {
        int row = base + rt + 64 * r;
        rv[r] = row < NN;
        rowc[r] = rv[r] ? row : (NN - 1);
    }
    {   // stage W (64x64 = 1024 float4) + bin
        const float4* wsrc = (const float4*)W;
        float4* wdst = (float4*)sW;
#pragma unroll
        for (int q = 0; q < 4; ++q) wdst[q * 256 + tid] = wsrc[q * 256 + tid];
        if (tid < 16) ((float4*)sBin)[tid] = ((const float4*)bin)[tid];
    }
    __syncthreads();
    float acc[4][16];
#pragma unroll
    for (int r = 0; r < 4; ++r)
#pragma unroll
        for (int c = 0; c < 16; ++c) acc[r][c] = 0.0f;

    for (int k4 = 0; k4 < 16; ++k4) {
        float bs[4];
        *(float4*)bs = ((const float4*)sBin)[k4];
        float xs[4][4];
#pragma unroll
        for (int r = 0; r < 4; ++r)
            *(float4*)xs[r] = *(const float4*)(in + (size_t)rowc[r] * HD + k4 * 4);
#pragma unroll
        for (int j = 0; j < 4; ++j) {
            float wv[16];
            const float4* wr4 = (const float4*)(sW + (k4 * 4 + j) * HD + cg);
#pragma unroll
            for (int q = 0; q < 4; ++q) ((float4*)wv)[q] = wr4[q];
#pragma unroll
            for (int r = 0; r < 4; ++r) {
                float hv = fmaxf(xs[r][j] + bs[j], 0.0f);
#pragma unroll
                for (int c = 0; c < 16; ++c) acc[r][c] = fmaf(hv, wv[c], acc[r][c]);
            }
        }
    }
    if (SELFLOOP) __syncthreads();  // drain all in-reads before in-place outB store
#pragma unroll
    for (int r = 0; r < 4; ++r) {
        if (!rv[r]) continue;
        float4* ha = (float4*)(outA + (size_t)rowc[r] * HD + cg);
        if (BIASRELU) {
            float bo[16];
#pragma unroll
            for (int q = 0; q < 4; ++q) ((float4*)bo)[q] = *(const float4*)(bout + cg + q * 4);
#pragma unroll
            for (int q = 0; q < 4; ++q) {
                float4 v;
                v.x = fmaxf(acc[r][q * 4 + 0] + bo[q * 4 + 0], 0.0f);
                v.y = fmaxf(acc[r][q * 4 + 1] + bo[q * 4 + 1], 0.0f);
                v.z = fmaxf(acc[r][q * 4 + 2] + bo[q * 4 + 2], 0.0f);
                v.w = fmaxf(acc[r][q * 4 + 3] + bo[q * 4 + 3], 0.0f);
                ha[q] = v;
            }
        } else {
            float di = SELFLOOP ? dinv[rowc[r]] : 0.0f;
            float d2 = di * di;
            float4* hb = SELFLOOP ? (float4*)(outB + (size_t)rowc[r] * HD + cg) : nullptr;
#pragma unroll
            for (int q = 0; q < 4; ++q) {
                float4 v = make_float4(acc[r][q * 4], acc[r][q * 4 + 1],
                                       acc[r][q * 4 + 2], acc[r][q * 4 + 3]);
                ha[q] = v;
                if (SELFLOOP)
                    hb[q] = make_float4(v.x * d2, v.y * d2, v.z * d2, v.w * d2);
            }
        }
    }
}

// One wave per edge, lane = feature. agg[dst] += h[src] * dinv[s]*w*dinv[d]
__global__ __launch_bounds__(256) void k_scatter(const int* __restrict__ src,
                                                 const int* __restrict__ dst,
                                                 const float* __restrict__ ew,
                                                 const float* __restrict__ dinv,
                                                 const float* __restrict__ h,
                                                 float* __restrict__ agg) {
    int e = blockIdx.x * 4 + (threadIdx.x >> 6);
    int lane = threadIdx.x & 63;
    if (e >= NE) return;
    int s = src[e];
    int d = dst[e];
    float nrm = dinv[s] * ew[e] * dinv[d];
    float v = h[(size_t)s * HD + lane] * nrm;
    atomicAdd(&agg[(size_t)d * HD + lane], v);
}

// logits = h3 @ Wm2 + bm2, softmax. Wm2 (4 KB) in LDS, 4 rows/thread.
__global__ __launch_bounds__(256, 4) void k_out(const float* __restrict__ h3,
                                                const float* __restrict__ Wm2,
                                                const float* __restrict__ bm2,
                                                float* __restrict__ out) {
    __shared__ float sW[HD * NC];  // 64*16 floats = 4 KB
    int tid = threadIdx.x;
    ((float4*)sW)[tid] = ((const float4*)Wm2)[tid];  // 256 float4 = whole Wm2
    __syncthreads();
    int base = blockIdx.x * 1024;
    int rowc[4];
    bool rv[4];
#pragma unroll
    for (int r = 0; r < 4; ++r) {
        int row = base + tid * 4 + r;
        rv[r] = row < NN;
        rowc[r] = rv[r] ? row : (NN - 1);
    }
    float acc[4][16];
#pragma unroll
    for (int r = 0; r < 4; ++r)
#pragma unroll
        for (int c = 0; c < 16; ++c) acc[r][c] = 0.0f;

    for (int k4 = 0; k4 < 16; ++k4) {
        float xs[4][4];
#pragma unroll
        for (int r = 0; r < 4; ++r)
            *(float4*)xs[r] = *(const float4*)(h3 + (size_t)rowc[r] * HD + k4 * 4);
#pragma unroll
        for (int j = 0; j < 4; ++j) {
            float wv[16];
            const float4* wr4 = (const float4*)(sW + (k4 * 4 + j) * NC);
#pragma unroll
            for (int q = 0; q < 4; ++q) ((float4*)wv)[q] = wr4[q];  // broadcast
#pragma unroll
            for (int r = 0; r < 4; ++r) {
                float xj = xs[r][j];
#pragma unroll
                for (int c = 0; c < 16; ++c) acc[r][c] = fmaf(xj, wv[c], acc[r][c]);
            }
        }
    }
    float bm[16];
#pragma unroll
    for (int q = 0; q < 4; ++q) ((float4*)bm)[q] = ((const float4*)bm2)[q];
#pragma unroll
    for (int r = 0; r < 4; ++r) {
        if (!rv[r]) continue;
        float l[16];
#pragma unroll
        for (int c = 0; c < 16; ++c) l[c] = acc[r][c] + bm[c];
        float m = l[0];
#pragma unroll
        for (int c = 1; c < 16; ++c) m = fmaxf(m, l[c]);
        float ssum = 0.0f;
#pragma unroll
        for (int c = 0; c < 16; ++c) {
            l[c] = expf(l[c] - m);
            ssum += l[c];
        }
        float inv = 1.0f / ssum;
        float4* op = (float4*)(out + (size_t)rowc[r] * NC);
#pragma unroll
        for (int q = 0; q < 4; ++q)
            op[q] = make_float4(l[q * 4] * inv, l[q * 4 + 1] * inv,
                                l[q * 4 + 2] * inv, l[q * 4 + 3] * inv);
    }
}

extern "C" void kernel_launch(void* const* d_in, const int* in_sizes, int n_in,
                              void* d_out, int out_size, void* d_ws, size_t ws_size,
                              hipStream_t stream) {
    const float* x   = (const float*)d_in[0];
    const int*   ei  = (const int*)d_in[1];   // (2, E): [0,E)=src, [E,2E)=dst
    const float* ew  = (const float*)d_in[2];
    const float* W1  = (const float*)d_in[3];
    const float* b1  = (const float*)d_in[4];
    const float* W2  = (const float*)d_in[5];
    const float* b2  = (const float*)d_in[6];
    const float* Wm1 = (const float*)d_in[7];
    const float* bm1 = (const float*)d_in[8];
    const float* Wm2 = (const float*)d_in[9];
    const float* bm2 = (const float*)d_in[10];
    float* out = (float*)d_out;

    char* base = (char*)d_ws;
    const size_t NB = (size_t)NN * HD * sizeof(float);  // 25,600,000 B
    float* dinv = (float*)base;
    float* A    = (float*)(base + 400128);       // h0 -> h2 -> h3
    float* B    = (float*)(base + 400128 + NB);  // agg1 -> agg2

    const int* src = ei;
    const int* dst = ei + NE;

    // degree -> dinv
    k_deg_init<<<dim3((NN + 255) / 256), dim3(256), 0, stream>>>(dinv);
    k_deg_accum<<<dim3(NE / 256), dim3(256), 0, stream>>>(dst, ew, dinv);
    k_dinv<<<dim3((NN + 255) / 256), dim3(256), 0, stream>>>(dinv);

    const int gemm_grid = (NN + 255) / 256;  // 391

    // layer 1: A = x@W1 ; B = A*dinv^2 (fused) ; scatter edges A->B
    k_gemm1<<<dim3(gemm_grid), dim3(256), 0, stream>>>(x, W1, dinv, A, B);
    k_scatter<<<dim3(NE / 4), dim3(256), 0, stream>>>(src, dst, ew, dinv, A, B);

    // layer 2: A = relu(B+b1)@W2 ; B = A*dinv^2 (fused, in-place on B) ; scatter
    k_gemm64<false, true><<<dim3(gemm_grid), dim3(256), 0, stream>>>(
        B, b1, W2, nullptr, dinv, A, B);
    k_scatter<<<dim3(NE / 4), dim3(256), 0, stream>>>(src, dst, ew, dinv, A, B);

    // MLP head: A = relu(relu(B+b2)@Wm1 + bm1) ; logits+softmax
    k_gemm64<true, false><<<dim3(gemm_grid), dim3(256), 0, stream>>>(
        B, b2, Wm1, bm1, nullptr, A, nullptr);
    k_out<<<dim3((NN + 1023) / 1024), dim3(256), 0, stream>>>(A, Wm2, bm2, out);
}

// Round 4
// 718.224 us; speedup vs baseline: 2.1865x; 1.5793x over previous
//
#include <hip/hip_runtime.h>
#include <cstdint>
#include <cstddef>

// Problem constants (match reference)
#define NN 100000   // nodes
#define NE 1600000  // edges
#define IN_F 256    // input feats
#define HD 64       // hidden width
#define NC 16       // classes
#define SCAN_B 98   // ceil(NN / 1024)

// ---------------------------------------------------------------------------
// Workspace layout (bytes):
//   dinv  @ 0          NN floats (400,000; padded region 400,128)
//   A     @ 400,128    NN*64 floats (h0 -> h2 -> h3)          25,600,000
//   B     @ 26,000,128 NN*64 floats (agg1 -> agg2; cnt early) 25,600,000
//   rs    @ 51,600,128 NN ints (row starts -> row ends)          400,000
//   bsum  @ 52,000,128 SCAN_B ints                                   392
//   bpref @ 52,000,520 SCAN_B ints                                   392
//   [FULL only] pairs @ 52,000,912  NE int2 (col, val bits)   12,800,000
// Configs (chosen by ws_size, constant per run -> graph-safe):
//   FULL (ws >= 64,800,912): CSR (col,val) pairs in ws.
//   DOUT (ws >= 52,000,912): CSR edge-ids in d_out (NE*4 B == out bytes),
//                            norm recomputed per edge (double indirection).
//   FALLBACK (else): R3 atomic-scatter path.
// ---------------------------------------------------------------------------

__global__ __launch_bounds__(256) void k_init(float* __restrict__ deg,
                                              int* __restrict__ cnt) {
    int i = blockIdx.x * 256 + threadIdx.x;
    if (i < NN) { deg[i] = 1.0f; cnt[i] = 0; }  // self-loop weight, zero count
}

// deg[d] += w ; cnt[d] += 1   (one pass over edges)
__global__ __launch_bounds__(256) void k_edge(const int* __restrict__ dst,
                                              const float* __restrict__ ew,
                                              float* __restrict__ deg,
                                              int* __restrict__ cnt) {
    int e = blockIdx.x * 256 + threadIdx.x;
    if (e < NE) {
        int d = dst[e];
        atomicAdd(&deg[d], ew[e]);
        atomicAdd(&cnt[d], 1);
    }
}

__global__ __launch_bounds__(256) void k_dinv(float* __restrict__ deg) {
    int i = blockIdx.x * 256 + threadIdx.x;
    if (i < NN) {
        float d = deg[i];
        deg[i] = d > 0.0f ? rsqrtf(d) : 0.0f;
    }
}

// --- exclusive scan of cnt[NN] -> rs[NN] (row starts), 1024 elems/block ---
__global__ __launch_bounds__(256) void k_scan1(const int* __restrict__ cnt,
                                               int* __restrict__ rs,
                                               int* __restrict__ bsum) {
    __shared__ int ss[256];
    int t = threadIdx.x;
    int base = blockIdx.x * 1024 + t * 4;
    int c0 = (base + 0 < NN) ? cnt[base + 0] : 0;
    int c1 = (base + 1 < NN) ? cnt[base + 1] : 0;
    int c2 = (base + 2 < NN) ? cnt[base + 2] : 0;
    int c3 = (base + 3 < NN) ? cnt[base + 3] : 0;
    int tsum = c0 + c1 + c2 + c3;
    ss[t] = tsum;
    __syncthreads();
    for (int off = 1; off < 256; off <<= 1) {
        int v = (t >= off) ? ss[t - off] : 0;
        __syncthreads();
        ss[t] += v;
        __syncthreads();
    }
    int excl = ss[t] - tsum;
    if (t == 255) bsum[blockIdx.x] = ss[255];
    if (base + 0 < NN) rs[base + 0] = excl;
    if (base + 1 < NN) rs[base + 1] = excl + c0;
    if (base + 2 < NN) rs[base + 2] = excl + c0 + c1;
    if (base + 3 < NN) rs[base + 3] = excl + c0 + c1 + c2;
}

__global__ __launch_bounds__(128) void k_scan2(const int* __restrict__ bsum,
                                               int* __restrict__ bpref) {
    __shared__ int ss[128];
    int t = threadIdx.x;
    int v = (t < SCAN_B) ? bsum[t] : 0;
    ss[t] = v;
    __syncthreads();
    for (int off = 1; off < 128; off <<= 1) {
        int u = (t >= off) ? ss[t - off] : 0;
        __syncthreads();
        ss[t] += u;
        __syncthreads();
    }
    if (t < SCAN_B) bpref[t] = ss[t] - v;
}

__global__ __launch_bounds__(256) void k_scan3(int* __restrict__ rs,
                                               const int* __restrict__ bpref) {
    int i = blockIdx.x * 256 + threadIdx.x;
    if (i < NN) rs[i] += bpref[i >> 10];
}

// --- CSR fill. atomicAdd on rs turns starts into ends; start(i)=rs[i-1]. ---
__global__ __launch_bounds__(256) void k_fill_full(const int* __restrict__ src,
                                                   const int* __restrict__ dst,
                                                   const float* __restrict__ ew,
                                                   const float* __restrict__ dinv,
                                                   int* __restrict__ rs,
                                                   int2* __restrict__ pairs) {
    int e = blockIdx.x * 256 + threadIdx.x;
    if (e >= NE) return;
    int s = src[e];
    int d = dst[e];
    int pos = atomicAdd(&rs[d], 1);
    float nv = dinv[s] * ew[e] * dinv[d];
    pairs[pos] = make_int2(s, __float_as_int(nv));
}

__global__ __launch_bounds__(256) void k_fill_eid(const int* __restrict__ dst,
                                                  int* __restrict__ rs,
                                                  int* __restrict__ eid) {
    int e = blockIdx.x * 256 + threadIdx.x;
    if (e >= NE) return;
    int pos = atomicAdd(&rs[dst[e]], 1);
    eid[pos] = e;
}

// --- aggregate: one wave per dst row, lane = feature.
//     agg[row] = dinv[row]^2 * h[row] + sum_edges norm * h[src] ---
__global__ __launch_bounds__(256) void k_agg_direct(const int* __restrict__ rs,
                                                    const int2* __restrict__ pairs,
                                                    const float* __restrict__ dinv,
                                                    const float* __restrict__ h,
                                                    float* __restrict__ agg) {
    int row = blockIdx.x * 4 + (threadIdx.x >> 6);
    int lane = threadIdx.x & 63;
    if (row >= NN) return;
    int end = rs[row];
    int start = row ? rs[row - 1] : 0;
    float di = dinv[row];
    float acc = h[(size_t)row * HD + lane] * di * di;
    int p = start;
    for (; p + 4 <= end; p += 4) {
        int2 v0 = pairs[p], v1 = pairs[p + 1], v2 = pairs[p + 2], v3 = pairs[p + 3];
        float h0 = h[(size_t)v0.x * HD + lane];
        float h1 = h[(size_t)v1.x * HD + lane];
        float h2 = h[(size_t)v2.x * HD + lane];
        float h3 = h[(size_t)v3.x * HD + lane];
        acc = fmaf(__int_as_float(v0.y), h0, acc);
        acc = fmaf(__int_as_float(v1.y), h1, acc);
        acc = fmaf(__int_as_float(v2.y), h2, acc);
        acc = fmaf(__int_as_float(v3.y), h3, acc);
    }
    for (; p < end; ++p) {
        int2 v = pairs[p];
        acc = fmaf(__int_as_float(v.y), h[(size_t)v.x * HD + lane], acc);
    }
    agg[(size_t)row * HD + lane] = acc;
}

__global__ __launch_bounds__(256) void k_agg_ind(const int* __restrict__ rs,
                                                 const int* __restrict__ eid,
                                                 const int* __restrict__ src,
                                                 const float* __restrict__ ew,
                                                 const float* __restrict__ dinv,
                                                 const float* __restrict__ h,
                                                 float* __restrict__ agg) {
    int row = blockIdx.x * 4 + (threadIdx.x >> 6);
    int lane = threadIdx.x & 63;
    if (row >= NN) return;
    int end = rs[row];
    int start = row ? rs[row - 1] : 0;
    float di = dinv[row];
    float acc = h[(size_t)row * HD + lane] * di * di;
    int p = start;
    for (; p + 4 <= end; p += 4) {
        int e0 = eid[p], e1 = eid[p + 1], e2 = eid[p + 2], e3 = eid[p + 3];
        int s0 = src[e0], s1 = src[e1], s2 = src[e2], s3 = src[e3];
        float n0 = dinv[s0] * ew[e0] * di;
        float n1 = dinv[s1] * ew[e1] * di;
        float n2 = dinv[s2] * ew[e2] * di;
        float n3 = dinv[s3] * ew[e3] * di;
        float h0 = h[(size_t)s0 * HD + lane];
        float h1 = h[(size_t)s1 * HD + lane];
        float h2 = h[(size_t)s2 * HD + lane];
        float h3 = h[(size_t)s3 * HD + lane];
        acc = fmaf(n0, h0, acc);
        acc = fmaf(n1, h1, acc);
        acc = fmaf(n2, h2, acc);
        acc = fmaf(n3, h3, acc);
    }
    for (; p < end; ++p) {
        int e = eid[p];
        int s = src[e];
        acc = fmaf(dinv[s] * ew[e] * di, h[(size_t)s * HD + lane], acc);
    }
    agg[(size_t)row * HD + lane] = acc;
}

// ---------------------------------------------------------------------------
// GEMMs (R2 structure, self-loop epilogue removed — aggregate handles it)
// ---------------------------------------------------------------------------
__global__ __launch_bounds__(256, 4) void k_gemm1(const float* __restrict__ x,
                                                  const float* __restrict__ W1,
                                                  float* __restrict__ h0) {
    __shared__ float sW[64 * HD];  // 16 KB chunk of W1
    int tid = threadIdx.x;
    int rt  = tid >> 2;
    int cg  = (tid & 3) * 16;
    int base = blockIdx.x * 256;
    int rowc[4];
    bool rv[4];
#pragma unroll
    for (int r = 0; r < 4; ++r) {
        int row = base + rt + 64 * r;
        rv[r] = row < NN;
        rowc[r] = rv[r] ? row : (NN - 1);
    }
    float acc[4][16];
#pragma unroll
    for (int r = 0; r < 4; ++r)
#pragma unroll
        for (int c = 0; c < 16; ++c) acc[r][c] = 0.0f;

    for (int kc = 0; kc < IN_F; kc += 64) {
        __syncthreads();
        {
            const float4* wsrc = (const float4*)(W1 + (size_t)kc * HD);
            float4* wdst = (float4*)sW;
#pragma unroll
            for (int q = 0; q < 4; ++q) wdst[q * 256 + tid] = wsrc[q * 256 + tid];
        }
        __syncthreads();
        for (int k4 = 0; k4 < 16; ++k4) {
            float xs[4][4];
#pragma unroll
            for (int r = 0; r < 4; ++r)
                *(float4*)xs[r] = *(const float4*)(x + (size_t)rowc[r] * IN_F + kc + k4 * 4);
#pragma unroll
            for (int j = 0; j < 4; ++j) {
                float wv[16];
                const float4* wr4 = (const float4*)(sW + (k4 * 4 + j) * HD + cg);
#pragma unroll
                for (int q = 0; q < 4; ++q) ((float4*)wv)[q] = wr4[q];
#pragma unroll
                for (int r = 0; r < 4; ++r) {
                    float xj = xs[r][j];
#pragma unroll
                    for (int c = 0; c < 16; ++c) acc[r][c] = fmaf(xj, wv[c], acc[r][c]);
                }
            }
        }
    }
#pragma unroll
    for (int r = 0; r < 4; ++r) {
        if (!rv[r]) continue;
        float4* hp = (float4*)(h0 + (size_t)rowc[r] * HD + cg);
#pragma unroll
        for (int q = 0; q < 4; ++q)
            hp[q] = make_float4(acc[r][q * 4], acc[r][q * 4 + 1],
                                acc[r][q * 4 + 2], acc[r][q * 4 + 3]);
    }
}

template <bool BIASRELU>
__global__ __launch_bounds__(256, 4) void k_gemm64(const float* __restrict__ in,
                                                   const float* __restrict__ bin,
                                                   const float* __restrict__ W,
                                                   const float* __restrict__ bout,
                                                   float* __restrict__ outA) {
    __shared__ float sW[HD * HD];
    __shared__ float sBin[HD];
    int tid = threadIdx.x;
    int rt  = tid >> 2;
    int cg  = (tid & 3) * 16;
    int base = blockIdx.x * 256;
    int rowc[4];
    bool rv[4];
#pragma unroll
    for (int r = 0; r < 4; ++r) {
        int row = base + rt + 64 * r;
        rv[r] = row < NN;
        rowc[r] = rv[r] ? row : (NN - 1);
    }
    {
        const float4* wsrc = (const float4*)W;
        float4* wdst = (float4*)sW;
#pragma unroll
        for (int q = 0; q < 4; ++q) wdst[q * 256 + tid] = wsrc[q * 256 + tid];
        if (tid < 16) ((float4*)sBin)[tid] = ((const float4*)bin)[tid];
    }
    __syncthreads();
    float acc[4][16];
#pragma unroll
    for (int r = 0; r < 4; ++r)
#pragma unroll
        for (int c = 0; c < 16; ++c) acc[r][c] = 0.0f;

    for (int k4 = 0; k4 < 16; ++k4) {
        float bs[4];
        *(float4*)bs = ((const float4*)sBin)[k4];
        float xs[4][4];
#pragma unroll
        for (int r = 0; r < 4; ++r)
            *(float4*)xs[r] = *(const float4*)(in + (size_t)rowc[r] * HD + k4 * 4);
#pragma unroll
        for (int j = 0; j < 4; ++j) {
            float wv[16];
            const float4* wr4 = (const float4*)(sW + (k4 * 4 + j) * HD + cg);
#pragma unroll
            for (int q = 0; q < 4; ++q) ((float4*)wv)[q] = wr4[q];
#pragma unroll
            for (int r = 0; r < 4; ++r) {
                float hv = fmaxf(xs[r][j] + bs[j], 0.0f);
#pragma unroll
                for (int c = 0; c < 16; ++c) acc[r][c] = fmaf(hv, wv[c], acc[r][c]);
            }
        }
    }
#pragma unroll
    for (int r = 0; r < 4; ++r) {
        if (!rv[r]) continue;
        float4* ha = (float4*)(outA + (size_t)rowc[r] * HD + cg);
        if (BIASRELU) {
            float bo[16];
#pragma unroll
            for (int q = 0; q < 4; ++q) ((float4*)bo)[q] = *(const float4*)(bout + cg + q * 4);
#pragma unroll
            for (int q = 0; q < 4; ++q) {
                float4 v;
                v.x = fmaxf(acc[r][q * 4 + 0] + bo[q * 4 + 0], 0.0f);
                v.y = fmaxf(acc[r][q * 4 + 1] + bo[q * 4 + 1], 0.0f);
                v.z = fmaxf(acc[r][q * 4 + 2] + bo[q * 4 + 2], 0.0f);
                v.w = fmaxf(acc[r][q * 4 + 3] + bo[q * 4 + 3], 0.0f);
                ha[q] = v;
            }
        } else {
#pragma unroll
            for (int q = 0; q < 4; ++q)
                ha[q] = make_float4(acc[r][q * 4], acc[r][q * 4 + 1],
                                    acc[r][q * 4 + 2], acc[r][q * 4 + 3]);
        }
    }
}

// --- fallback path kernels (ws too small for CSR) ---
__global__ __launch_bounds__(256) void k_selfloop(const float* __restrict__ h,
                                                  const float* __restrict__ dinv,
                                                  float* __restrict__ agg) {
    int i = blockIdx.x * 256 + threadIdx.x;
    if (i >= NN * (HD / 4)) return;
    int row = i / (HD / 4);
    float di = dinv[row];
    float d2 = di * di;
    float4 v = ((const float4*)h)[i];
    ((float4*)agg)[i] = make_float4(v.x * d2, v.y * d2, v.z * d2, v.w * d2);
}

__global__ __launch_bounds__(256) void k_scatter(const int* __restrict__ src,
                                                 const int* __restrict__ dst,
                                                 const float* __restrict__ ew,
                                                 const float* __restrict__ dinv,
                                                 const float* __restrict__ h,
                                                 float* __restrict__ agg) {
    int e = blockIdx.x * 4 + (threadIdx.x >> 6);
    int lane = threadIdx.x & 63;
    if (e >= NE) return;
    int s = src[e];
    int d = dst[e];
    float nrm = dinv[s] * ew[e] * dinv[d];
    float v = h[(size_t)s * HD + lane] * nrm;
    atomicAdd(&agg[(size_t)d * HD + lane], v);
}

// logits = h3 @ Wm2 + bm2, softmax. Wm2 (4 KB) in LDS, 4 rows/thread.
__global__ __launch_bounds__(256, 4) void k_out(const float* __restrict__ h3,
                                                const float* __restrict__ Wm2,
                                                const float* __restrict__ bm2,
                                                float* __restrict__ out) {
    __shared__ float sW[HD * NC];
    int tid = threadIdx.x;
    ((float4*)sW)[tid] = ((const float4*)Wm2)[tid];
    __syncthreads();
    int base = blockIdx.x * 1024;
    int rowc[4];
    bool rv[4];
#pragma unroll
    for (int r = 0; r < 4; ++r) {
        int row = base + tid * 4 + r;
        rv[r] = row < NN;
        rowc[r] = rv[r] ? row : (NN - 1);
    }
    float acc[4][16];
#pragma unroll
    for (int r = 0; r < 4; ++r)
#pragma unroll
        for (int c = 0; c < 16; ++c) acc[r][c] = 0.0f;

    for (int k4 = 0; k4 < 16; ++k4) {
        float xs[4][4];
#pragma unroll
        for (int r = 0; r < 4; ++r)
            *(float4*)xs[r] = *(const float4*)(h3 + (size_t)rowc[r] * HD + k4 * 4);
#pragma unroll
        for (int j = 0; j < 4; ++j) {
            float wv[16];
            const float4* wr4 = (const float4*)(sW + (k4 * 4 + j) * NC);
#pragma unroll
            for (int q = 0; q < 4; ++q) ((float4*)wv)[q] = wr4[q];
#pragma unroll
            for (int r = 0; r < 4; ++r) {
                float xj = xs[r][j];
#pragma unroll
                for (int c = 0; c < 16; ++c) acc[r][c] = fmaf(xj, wv[c], acc[r][c]);
            }
        }
    }
    float bm[16];
#pragma unroll
    for (int q = 0; q < 4; ++q) ((float4*)bm)[q] = ((const float4*)bm2)[q];
#pragma unroll
    for (int r = 0; r < 4; ++r) {
        if (!rv[r]) continue;
        float l[16];
#pragma unroll
        for (int c = 0; c < 16; ++c) l[c] = acc[r][c] + bm[c];
        float m = l[0];
#pragma unroll
        for (int c = 1; c < 16; ++c) m = fmaxf(m, l[c]);
        float ssum = 0.0f;
#pragma unroll
        for (int c = 0; c < 16; ++c) {
            l[c] = expf(l[c] - m);
            ssum += l[c];
        }
        float inv = 1.0f / ssum;
        float4* op = (float4*)(out + (size_t)rowc[r] * NC);
#pragma unroll
        for (int q = 0; q < 4; ++q)
            op[q] = make_float4(l[q * 4] * inv, l[q * 4 + 1] * inv,
                                l[q * 4 + 2] * inv, l[q * 4 + 3] * inv);
    }
}

extern "C" void kernel_launch(void* const* d_in, const int* in_sizes, int n_in,
                              void* d_out, int out_size, void* d_ws, size_t ws_size,
                              hipStream_t stream) {
    const float* x   = (const float*)d_in[0];
    const int*   ei  = (const int*)d_in[1];   // (2, E): [0,E)=src, [E,2E)=dst
    const float* ew  = (const float*)d_in[2];
    const float* W1  = (const float*)d_in[3];
    const float* b1  = (const float*)d_in[4];
    const float* W2  = (const float*)d_in[5];
    const float* b2  = (const float*)d_in[6];
    const float* Wm1 = (const float*)d_in[7];
    const float* bm1 = (const float*)d_in[8];
    const float* Wm2 = (const float*)d_in[9];
    const float* bm2 = (const float*)d_in[10];
    float* out = (float*)d_out;

    char* base = (char*)d_ws;
    float* dinv = (float*)base;
    float* A    = (float*)(base + 400128);
    float* B    = (float*)(base + 26000128);
    int*   rs    = (int*)(base + 51600128);
    int*   bsum  = (int*)(base + 52000128);
    int*   bpref = (int*)(base + 52000520);
    int2*  pairs = (int2*)(base + 52000912);
    int*   cnt   = (int*)B;  // B dead until aggregate1 writes it

    const int* src = ei;
    const int* dst = ei + NE;

    const bool full = ws_size >= (size_t)64800912;
    const bool douta = !full && ws_size >= (size_t)52000912;
    const int g_node = (NN + 255) / 256;        // 391
    const int g_edge = NE / 256;                // 6250
    const int g_gemm = (NN + 255) / 256;        // 391
    const int g_agg  = (NN + 3) / 4;            // 25000

    if (full || douta) {
        // --- degree + histogram + dinv ---
        k_init<<<dim3(g_node), dim3(256), 0, stream>>>(dinv, cnt);
        k_edge<<<dim3(g_edge), dim3(256), 0, stream>>>(dst, ew, dinv, cnt);
        k_dinv<<<dim3(g_node), dim3(256), 0, stream>>>(dinv);
        // --- scan cnt -> rs (row starts) ---
        k_scan1<<<dim3(SCAN_B), dim3(256), 0, stream>>>(cnt, rs, bsum);
        k_scan2<<<dim3(1), dim3(128), 0, stream>>>(bsum, bpref);
        k_scan3<<<dim3(g_node), dim3(256), 0, stream>>>(rs, bpref);
        // --- fill CSR (rs becomes row ends) ---
        if (full)
            k_fill_full<<<dim3(g_edge), dim3(256), 0, stream>>>(src, dst, ew, dinv, rs, pairs);
        else
            k_fill_eid<<<dim3(g_edge), dim3(256), 0, stream>>>(dst, rs, (int*)d_out);
        // --- layer 1 ---
        k_gemm1<<<dim3(g_gemm), dim3(256), 0, stream>>>(x, W1, A);
        if (full)
            k_agg_direct<<<dim3(g_agg), dim3(256), 0, stream>>>(rs, pairs, dinv, A, B);
        else
            k_agg_ind<<<dim3(g_agg), dim3(256), 0, stream>>>(rs, (int*)d_out, src, ew, dinv, A, B);
        // --- layer 2 ---
        k_gemm64<false><<<dim3(g_gemm), dim3(256), 0, stream>>>(B, b1, W2, nullptr, A);
        if (full)
            k_agg_direct<<<dim3(g_agg), dim3(256), 0, stream>>>(rs, pairs, dinv, A, B);
        else
            k_agg_ind<<<dim3(g_agg), dim3(256), 0, stream>>>(rs, (int*)d_out, src, ew, dinv, A, B);
        // --- MLP head + softmax ---
        k_gemm64<true><<<dim3(g_gemm), dim3(256), 0, stream>>>(B, b2, Wm1, bm1, A);
        k_out<<<dim3((NN + 1023) / 1024), dim3(256), 0, stream>>>(A, Wm2, bm2, out);
    } else {
        // --- fallback: atomic scatter (R3 path) ---
        k_init<<<dim3(g_node), dim3(256), 0, stream>>>(dinv, cnt);  // cnt harmless
        k_edge<<<dim3(g_edge), dim3(256), 0, stream>>>(dst, ew, dinv, cnt);
        k_dinv<<<dim3(g_node), dim3(256), 0, stream>>>(dinv);
        k_gemm1<<<dim3(g_gemm), dim3(256), 0, stream>>>(x, W1, A);
        k_selfloop<<<dim3((NN * (HD / 4) + 255) / 256), dim3(256), 0, stream>>>(A, dinv, B);
        k_scatter<<<dim3(NE / 4), dim3(256), 0, stream>>>(src, dst, ew, dinv, A, B);
        k_gemm64<false><<<dim3(g_gemm), dim3(256), 0, stream>>>(B, b1, W2, nullptr, A);
        k_selfloop<<<dim3((NN * (HD / 4) + 255) / 256), dim3(256), 0, stream>>>(A, dinv, B);
        k_scatter<<<dim3(NE / 4), dim3(256), 0, stream>>>(src, dst, ew, dinv, A, B);
        k_gemm64<true><<<dim3(g_gemm), dim3(256), 0, stream>>>(B, b2, Wm1, bm1, A);
        k_out<<<dim3((NN + 1023) / 1024), dim3(256), 0, stream>>>(A, Wm2, bm2, out);
    }
}

// Round 5
// 620.376 us; speedup vs baseline: 2.5314x; 1.1577x over previous
//
#include <hip/hip_runtime.h>
#include <cstdint>
#include <cstddef>

// Problem constants (match reference)
#define NN 100000   // nodes
#define NE 1600000  // edges
#define IN_F 256    // input feats
#define HD 64       // hidden width
#define NC 16       // classes
#define SCAN_B 98   // ceil(NN / 1024)
#define G1B 391     // gemm1 blocks = ceil(NN/256)
#define HISTB 3125  // hist blocks = ceil(NE/512)

// ---------------------------------------------------------------------------
// Workspace layout (bytes):
//   dinv  @ 0          NN floats                                  400,000
//   A     @ 400,128    NN*64 floats (h0 -> h2 -> h3)           25,600,000
//   B     @ 26,000,128 NN*64 floats (agg1 -> agg2; cnt early)  25,600,000
//   rs    @ 51,600,128 NN ints (row starts -> row ends)           400,000
//   bsum  @ 52,000,128 SCAN_B ints
//   bpref @ 52,000,520 SCAN_B ints
//   [FULL only] pairs @ 52,000,912  NE int2 (src, ew bits)    12,800,000
// Configs (by ws_size, constant per run -> graph-safe):
//   FULL (ws >= 64,800,912): CSR (src, ew) pairs in ws; norm inline in agg.
//   DOUT (ws >= 52,000,912): CSR edge-ids in d_out (NE*4 B == out bytes).
//   FALLBACK (else): atomic-scatter path.
// ---------------------------------------------------------------------------

__global__ __launch_bounds__(256) void k_zero(int* __restrict__ cnt) {
    int i = blockIdx.x * 256 + threadIdx.x;
    if (i < NN) cnt[i] = 0;
}

// ---------------------------------------------------------------------------
// Fused: blocks [0, G1B) -> h0 = x @ W1 ; blocks [G1B, G1B+HISTB) -> cnt hist.
// Latency-bound hist waves co-schedule with VALU-bound gemm waves.
// ---------------------------------------------------------------------------
__global__ __launch_bounds__(256, 4) void k_g1_hist(const float* __restrict__ x,
                                                    const float* __restrict__ W1,
                                                    float* __restrict__ h0,
                                                    const int* __restrict__ dst,
                                                    int* __restrict__ cnt) {
    __shared__ float sW[64 * HD];  // 16 KB (gemm blocks only)
    int tid = threadIdx.x;
    if (blockIdx.x >= G1B) {
        int e = (blockIdx.x - G1B) * 512 + tid;
        if (e < NE) atomicAdd(&cnt[dst[e]], 1);
        e += 256;
        if (e < NE) atomicAdd(&cnt[dst[e]], 1);
        return;
    }
    int rt  = tid >> 2;
    int cg  = (tid & 3) * 16;
    int base = blockIdx.x * 256;
    int rowc[4];
    bool rv[4];
#pragma unroll
    for (int r = 0; r < 4; ++r) {
        int row = base + rt + 64 * r;
        rv[r] = row < NN;
        rowc[r] = rv[r] ? row : (NN - 1);
    }
    float acc[4][16];
#pragma unroll
    for (int r = 0; r < 4; ++r)
#pragma unroll
        for (int c = 0; c < 16; ++c) acc[r][c] = 0.0f;

    for (int kc = 0; kc < IN_F; kc += 64) {
        __syncthreads();
        {
            const float4* wsrc = (const float4*)(W1 + (size_t)kc * HD);
            float4* wdst = (float4*)sW;
#pragma unroll
            for (int q = 0; q < 4; ++q) wdst[q * 256 + tid] = wsrc[q * 256 + tid];
        }
        __syncthreads();
        for (int k4 = 0; k4 < 16; ++k4) {
            float xs[4][4];
#pragma unroll
            for (int r = 0; r < 4; ++r)
                *(float4*)xs[r] = *(const float4*)(x + (size_t)rowc[r] * IN_F + kc + k4 * 4);
#pragma unroll
            for (int j = 0; j < 4; ++j) {
                float wv[16];
                const float4* wr4 = (const float4*)(sW + (k4 * 4 + j) * HD + cg);
#pragma unroll
                for (int q = 0; q < 4; ++q) ((float4*)wv)[q] = wr4[q];
#pragma unroll
                for (int r = 0; r < 4; ++r) {
                    float xj = xs[r][j];
#pragma unroll
                    for (int c = 0; c < 16; ++c) acc[r][c] = fmaf(xj, wv[c], acc[r][c]);
                }
            }
        }
    }
#pragma unroll
    for (int r = 0; r < 4; ++r) {
        if (!rv[r]) continue;
        float4* hp = (float4*)(h0 + (size_t)rowc[r] * HD + cg);
#pragma unroll
        for (int q = 0; q < 4; ++q)
            hp[q] = make_float4(acc[r][q * 4], acc[r][q * 4 + 1],
                                acc[r][q * 4 + 2], acc[r][q * 4 + 3]);
    }
}

// --- exclusive scan of cnt[NN] -> rs[NN] (row starts), 1024 elems/block ---
__global__ __launch_bounds__(256) void k_scan1(const int* __restrict__ cnt,
                                               int* __restrict__ rs,
                                               int* __restrict__ bsum) {
    __shared__ int ss[256];
    int t = threadIdx.x;
    int base = blockIdx.x * 1024 + t * 4;
    int c0 = (base + 0 < NN) ? cnt[base + 0] : 0;
    int c1 = (base + 1 < NN) ? cnt[base + 1] : 0;
    int c2 = (base + 2 < NN) ? cnt[base + 2] : 0;
    int c3 = (base + 3 < NN) ? cnt[base + 3] : 0;
    int tsum = c0 + c1 + c2 + c3;
    ss[t] = tsum;
    __syncthreads();
    for (int off = 1; off < 256; off <<= 1) {
        int v = (t >= off) ? ss[t - off] : 0;
        __syncthreads();
        ss[t] += v;
        __syncthreads();
    }
    int excl = ss[t] - tsum;
    if (t == 255) bsum[blockIdx.x] = ss[255];
    if (base + 0 < NN) rs[base + 0] = excl;
    if (base + 1 < NN) rs[base + 1] = excl + c0;
    if (base + 2 < NN) rs[base + 2] = excl + c0 + c1;
    if (base + 3 < NN) rs[base + 3] = excl + c0 + c1 + c2;
}

__global__ __launch_bounds__(128) void k_scan2(const int* __restrict__ bsum,
                                               int* __restrict__ bpref) {
    __shared__ int ss[128];
    int t = threadIdx.x;
    int v = (t < SCAN_B) ? bsum[t] : 0;
    ss[t] = v;
    __syncthreads();
    for (int off = 1; off < 128; off <<= 1) {
        int u = (t >= off) ? ss[t - off] : 0;
        __syncthreads();
        ss[t] += u;
        __syncthreads();
    }
    if (t < SCAN_B) bpref[t] = ss[t] - v;
}

__global__ __launch_bounds__(256) void k_scan3(int* __restrict__ rs,
                                               const int* __restrict__ bpref) {
    int i = blockIdx.x * 256 + threadIdx.x;
    if (i < NN) rs[i] += bpref[i >> 10];
}

// --- CSR fill. atomicAdd on rs turns starts into ends; start(i)=rs[i-1]. ---
__global__ __launch_bounds__(256) void k_fill_full(const int* __restrict__ src,
                                                   const int* __restrict__ dst,
                                                   const float* __restrict__ ew,
                                                   int* __restrict__ rs,
                                                   int2* __restrict__ pairs) {
    int e = blockIdx.x * 256 + threadIdx.x;
    if (e >= NE) return;
    int pos = atomicAdd(&rs[dst[e]], 1);
    pairs[pos] = make_int2(src[e], __float_as_int(ew[e]));
}

__global__ __launch_bounds__(256) void k_fill_eid(const int* __restrict__ dst,
                                                  int* __restrict__ rs,
                                                  int* __restrict__ eid) {
    int e = blockIdx.x * 256 + threadIdx.x;
    if (e >= NE) return;
    int pos = atomicAdd(&rs[dst[e]], 1);
    eid[pos] = e;
}

// --- deg/dinv from CSR (no atomics): dinv[i] = rsqrt(1 + sum ew in row) ---
__global__ __launch_bounds__(256) void k_degdinv_full(const int* __restrict__ rs,
                                                      const int2* __restrict__ pairs,
                                                      float* __restrict__ dinv) {
    int i = blockIdx.x * 256 + threadIdx.x;
    if (i >= NN) return;
    int end = rs[i];
    int start = i ? rs[i - 1] : 0;
    float s = 1.0f;
    for (int p = start; p < end; ++p) s += __int_as_float(pairs[p].y);
    dinv[i] = s > 0.0f ? rsqrtf(s) : 0.0f;
}

__global__ __launch_bounds__(256) void k_degdinv_ind(const int* __restrict__ rs,
                                                     const int* __restrict__ eid,
                                                     const float* __restrict__ ew,
                                                     float* __restrict__ dinv) {
    int i = blockIdx.x * 256 + threadIdx.x;
    if (i >= NN) return;
    int end = rs[i];
    int start = i ? rs[i - 1] : 0;
    float s = 1.0f;
    for (int p = start; p < end; ++p) s += ew[eid[p]];
    dinv[i] = s > 0.0f ? rsqrtf(s) : 0.0f;
}

// --- aggregate: one wave per dst row, lane = feature. norm inline:
//     agg[row] = dinv[row]^2 * h[row] + sum_e dinv[s]*ew*dinv[row] * h[s] ---
__global__ __launch_bounds__(256) void k_agg_full(const int* __restrict__ rs,
                                                  const int2* __restrict__ pairs,
                                                  const float* __restrict__ dinv,
                                                  const float* __restrict__ h,
                                                  float* __restrict__ agg) {
    int row = blockIdx.x * 4 + (threadIdx.x >> 6);
    int lane = threadIdx.x & 63;
    if (row >= NN) return;
    int end = rs[row];
    int start = row ? rs[row - 1] : 0;
    float di = dinv[row];
    float acc = h[(size_t)row * HD + lane] * di * di;
    int p = start;
    for (; p + 4 <= end; p += 4) {
        int2 v0 = pairs[p], v1 = pairs[p + 1], v2 = pairs[p + 2], v3 = pairs[p + 3];
        float n0 = dinv[v0.x] * __int_as_float(v0.y) * di;
        float n1 = dinv[v1.x] * __int_as_float(v1.y) * di;
        float n2 = dinv[v2.x] * __int_as_float(v2.y) * di;
        float n3 = dinv[v3.x] * __int_as_float(v3.y) * di;
        float h0 = h[(size_t)v0.x * HD + lane];
        float h1 = h[(size_t)v1.x * HD + lane];
        float h2 = h[(size_t)v2.x * HD + lane];
        float h3 = h[(size_t)v3.x * HD + lane];
        acc = fmaf(n0, h0, acc);
        acc = fmaf(n1, h1, acc);
        acc = fmaf(n2, h2, acc);
        acc = fmaf(n3, h3, acc);
    }
    for (; p < end; ++p) {
        int2 v = pairs[p];
        acc = fmaf(dinv[v.x] * __int_as_float(v.y) * di, h[(size_t)v.x * HD + lane], acc);
    }
    agg[(size_t)row * HD + lane] = acc;
}

__global__ __launch_bounds__(256) void k_agg_ind(const int* __restrict__ rs,
                                                 const int* __restrict__ eid,
                                                 const int* __restrict__ src,
                                                 const float* __restrict__ ew,
                                                 const float* __restrict__ dinv,
                                                 const float* __restrict__ h,
                                                 float* __restrict__ agg) {
    int row = blockIdx.x * 4 + (threadIdx.x >> 6);
    int lane = threadIdx.x & 63;
    if (row >= NN) return;
    int end = rs[row];
    int start = row ? rs[row - 1] : 0;
    float di = dinv[row];
    float acc = h[(size_t)row * HD + lane] * di * di;
    int p = start;
    for (; p + 4 <= end; p += 4) {
        int e0 = eid[p], e1 = eid[p + 1], e2 = eid[p + 2], e3 = eid[p + 3];
        int s0 = src[e0], s1 = src[e1], s2 = src[e2], s3 = src[e3];
        float n0 = dinv[s0] * ew[e0] * di;
        float n1 = dinv[s1] * ew[e1] * di;
        float n2 = dinv[s2] * ew[e2] * di;
        float n3 = dinv[s3] * ew[e3] * di;
        float h0 = h[(size_t)s0 * HD + lane];
        float h1 = h[(size_t)s1 * HD + lane];
        float h2 = h[(size_t)s2 * HD + lane];
        float h3 = h[(size_t)s3 * HD + lane];
        acc = fmaf(n0, h0, acc);
        acc = fmaf(n1, h1, acc);
        acc = fmaf(n2, h2, acc);
        acc = fmaf(n3, h3, acc);
    }
    for (; p < end; ++p) {
        int e = eid[p];
        int s = src[e];
        acc = fmaf(dinv[s] * ew[e] * di, h[(size_t)s * HD + lane], acc);
    }
    agg[(size_t)row * HD + lane] = acc;
}

// ---------------------------------------------------------------------------
// Standalone gemm1 (fallback path) + gemm64 + out (all paths)
// ---------------------------------------------------------------------------
__global__ __launch_bounds__(256, 4) void k_gemm1(const float* __restrict__ x,
                                                  const float* __restrict__ W1,
                                                  float* __restrict__ h0) {
    __shared__ float sW[64 * HD];
    int tid = threadIdx.x;
    int rt  = tid >> 2;
    int cg  = (tid & 3) * 16;
    int base = blockIdx.x * 256;
    int rowc[4];
    bool rv[4];
#pragma unroll
    for (int r = 0; r < 4; ++r) {
        int row = base + rt + 64 * r;
        rv[r] = row < NN;
        rowc[r] = rv[r] ? row : (NN - 1);
    }
    float acc[4][16];
#pragma unroll
    for (int r = 0; r < 4; ++r)
#pragma unroll
        for (int c = 0; c < 16; ++c) acc[r][c] = 0.0f;

    for (int kc = 0; kc < IN_F; kc += 64) {
        __syncthreads();
        {
            const float4* wsrc = (const float4*)(W1 + (size_t)kc * HD);
            float4* wdst = (float4*)sW;
#pragma unroll
            for (int q = 0; q < 4; ++q) wdst[q * 256 + tid] = wsrc[q * 256 + tid];
        }
        __syncthreads();
        for (int k4 = 0; k4 < 16; ++k4) {
            float xs[4][4];
#pragma unroll
            for (int r = 0; r < 4; ++r)
                *(float4*)xs[r] = *(const float4*)(x + (size_t)rowc[r] * IN_F + kc + k4 * 4);
#pragma unroll
            for (int j = 0; j < 4; ++j) {
                float wv[16];
                const float4* wr4 = (const float4*)(sW + (k4 * 4 + j) * HD + cg);
#pragma unroll
                for (int q = 0; q < 4; ++q) ((float4*)wv)[q] = wr4[q];
#pragma unroll
                for (int r = 0; r < 4; ++r) {
                    float xj = xs[r][j];
#pragma unroll
                    for (int c = 0; c < 16; ++c) acc[r][c] = fmaf(xj, wv[c], acc[r][c]);
                }
            }
        }
    }
#pragma unroll
    for (int r = 0; r < 4; ++r) {
        if (!rv[r]) continue;
        float4* hp = (float4*)(h0 + (size_t)rowc[r] * HD + cg);
#pragma unroll
        for (int q = 0; q < 4; ++q)
            hp[q] = make_float4(acc[r][q * 4], acc[r][q * 4 + 1],
                                acc[r][q * 4 + 2], acc[r][q * 4 + 3]);
    }
}

template <bool BIASRELU>
__global__ __launch_bounds__(256, 4) void k_gemm64(const float* __restrict__ in,
                                                   const float* __restrict__ bin,
                                                   const float* __restrict__ W,
                                                   const float* __restrict__ bout,
                                                   float* __restrict__ outA) {
    __shared__ float sW[HD * HD];
    __shared__ float sBin[HD];
    int tid = threadIdx.x;
    int rt  = tid >> 2;
    int cg  = (tid & 3) * 16;
    int base = blockIdx.x * 256;
    int rowc[4];
    bool rv[4];
#pragma unroll
    for (int r = 0; r < 4; ++r) {
        int row = base + rt + 64 * r;
        rv[r] = row < NN;
        rowc[r] = rv[r] ? row : (NN - 1);
    }
    {
        const float4* wsrc = (const float4*)W;
        float4* wdst = (float4*)sW;
#pragma unroll
        for (int q = 0; q < 4; ++q) wdst[q * 256 + tid] = wsrc[q * 256 + tid];
        if (tid < 16) ((float4*)sBin)[tid] = ((const float4*)bin)[tid];
    }
    __syncthreads();
    float acc[4][16];
#pragma unroll
    for (int r = 0; r < 4; ++r)
#pragma unroll
        for (int c = 0; c < 16; ++c) acc[r][c] = 0.0f;

    for (int k4 = 0; k4 < 16; ++k4) {
        float bs[4];
        *(float4*)bs = ((const float4*)sBin)[k4];
        float xs[4][4];
#pragma unroll
        for (int r = 0; r < 4; ++r)
            *(float4*)xs[r] = *(const float4*)(in + (size_t)rowc[r] * HD + k4 * 4);
#pragma unroll
        for (int j = 0; j < 4; ++j) {
            float wv[16];
            const float4* wr4 = (const float4*)(sW + (k4 * 4 + j) * HD + cg);
#pragma unroll
            for (int q = 0; q < 4; ++q) ((float4*)wv)[q] = wr4[q];
#pragma unroll
            for (int r = 0; r < 4; ++r) {
                float hv = fmaxf(xs[r][j] + bs[j], 0.0f);
#pragma unroll
                for (int c = 0; c < 16; ++c) acc[r][c] = fmaf(hv, wv[c], acc[r][c]);
            }
        }
    }
#pragma unroll
    for (int r = 0; r < 4; ++r) {
        if (!rv[r]) continue;
        float4* ha = (float4*)(outA + (size_t)rowc[r] * HD + cg);
        if (BIASRELU) {
            float bo[16];
#pragma unroll
            for (int q = 0; q < 4; ++q) ((float4*)bo)[q] = *(const float4*)(bout + cg + q * 4);
#pragma unroll
            for (int q = 0; q < 4; ++q) {
                float4 v;
                v.x = fmaxf(acc[r][q * 4 + 0] + bo[q * 4 + 0], 0.0f);
                v.y = fmaxf(acc[r][q * 4 + 1] + bo[q * 4 + 1], 0.0f);
                v.z = fmaxf(acc[r][q * 4 + 2] + bo[q * 4 + 2], 0.0f);
                v.w = fmaxf(acc[r][q * 4 + 3] + bo[q * 4 + 3], 0.0f);
                ha[q] = v;
            }
        } else {
#pragma unroll
            for (int q = 0; q < 4; ++q)
                ha[q] = make_float4(acc[r][q * 4], acc[r][q * 4 + 1],
                                    acc[r][q * 4 + 2], acc[r][q * 4 + 3]);
        }
    }
}

// --- fallback path kernels ---
__global__ __launch_bounds__(256) void k_init_fb(float* __restrict__ deg) {
    int i = blockIdx.x * 256 + threadIdx.x;
    if (i < NN) deg[i] = 1.0f;
}

__global__ __launch_bounds__(256) void k_edge_fb(const int* __restrict__ dst,
                                                 const float* __restrict__ ew,
                                                 float* __restrict__ deg) {
    int e = blockIdx.x * 256 + threadIdx.x;
    if (e < NE) atomicAdd(&deg[dst[e]], ew[e]);
}

__global__ __launch_bounds__(256) void k_dinv_fb(float* __restrict__ deg) {
    int i = blockIdx.x * 256 + threadIdx.x;
    if (i < NN) {
        float d = deg[i];
        deg[i] = d > 0.0f ? rsqrtf(d) : 0.0f;
    }
}

__global__ __launch_bounds__(256) void k_selfloop(const float* __restrict__ h,
                                                  const float* __restrict__ dinv,
                                                  float* __restrict__ agg) {
    int i = blockIdx.x * 256 + threadIdx.x;
    if (i >= NN * (HD / 4)) return;
    int row = i / (HD / 4);
    float di = dinv[row];
    float d2 = di * di;
    float4 v = ((const float4*)h)[i];
    ((float4*)agg)[i] = make_float4(v.x * d2, v.y * d2, v.z * d2, v.w * d2);
}

__global__ __launch_bounds__(256) void k_scatter(const int* __restrict__ src,
                                                 const int* __restrict__ dst,
                                                 const float* __restrict__ ew,
                                                 const float* __restrict__ dinv,
                                                 const float* __restrict__ h,
                                                 float* __restrict__ agg) {
    int e = blockIdx.x * 4 + (threadIdx.x >> 6);
    int lane = threadIdx.x & 63;
    if (e >= NE) return;
    int s = src[e];
    int d = dst[e];
    float nrm = dinv[s] * ew[e] * dinv[d];
    float v = h[(size_t)s * HD + lane] * nrm;
    atomicAdd(&agg[(size_t)d * HD + lane], v);
}

// logits = h3 @ Wm2 + bm2, softmax. Wm2 (4 KB) in LDS, 4 rows/thread.
__global__ __launch_bounds__(256, 4) void k_out(const float* __restrict__ h3,
                                                const float* __restrict__ Wm2,
                                                const float* __restrict__ bm2,
                                                float* __restrict__ out) {
    __shared__ float sW[HD * NC];
    int tid = threadIdx.x;
    ((float4*)sW)[tid] = ((const float4*)Wm2)[tid];
    __syncthreads();
    int base = blockIdx.x * 1024;
    int rowc[4];
    bool rv[4];
#pragma unroll
    for (int r = 0; r < 4; ++r) {
        int row = base + tid * 4 + r;
        rv[r] = row < NN;
        rowc[r] = rv[r] ? row : (NN - 1);
    }
    float acc[4][16];
#pragma unroll
    for (int r = 0; r < 4; ++r)
#pragma unroll
        for (int c = 0; c < 16; ++c) acc[r][c] = 0.0f;

    for (int k4 = 0; k4 < 16; ++k4) {
        float xs[4][4];
#pragma unroll
        for (int r = 0; r < 4; ++r)
            *(float4*)xs[r] = *(const float4*)(h3 + (size_t)rowc[r] * HD + k4 * 4);
#pragma unroll
        for (int j = 0; j < 4; ++j) {
            float wv[16];
            const float4* wr4 = (const float4*)(sW + (k4 * 4 + j) * NC);
#pragma unroll
            for (int q = 0; q < 4; ++q) ((float4*)wv)[q] = wr4[q];
#pragma unroll
            for (int r = 0; r < 4; ++r) {
                float xj = xs[r][j];
#pragma unroll
                for (int c = 0; c < 16; ++c) acc[r][c] = fmaf(xj, wv[c], acc[r][c]);
            }
        }
    }
    float bm[16];
#pragma unroll
    for (int q = 0; q < 4; ++q) ((float4*)bm)[q] = ((const float4*)bm2)[q];
#pragma unroll
    for (int r = 0; r < 4; ++r) {
        if (!rv[r]) continue;
        float l[16];
#pragma unroll
        for (int c = 0; c < 16; ++c) l[c] = acc[r][c] + bm[c];
        float m = l[0];
#pragma unroll
        for (int c = 1; c < 16; ++c) m = fmaxf(m, l[c]);
        float ssum = 0.0f;
#pragma unroll
        for (int c = 0; c < 16; ++c) {
            l[c] = expf(l[c] - m);
            ssum += l[c];
        }
        float inv = 1.0f / ssum;
        float4* op = (float4*)(out + (size_t)rowc[r] * NC);
#pragma unroll
        for (int q = 0; q < 4; ++q)
            op[q] = make_float4(l[q * 4] * inv, l[q * 4 + 1] * inv,
                                l[q * 4 + 2] * inv, l[q * 4 + 3] * inv);
    }
}

extern "C" void kernel_launch(void* const* d_in, const int* in_sizes, int n_in,
                              void* d_out, int out_size, void* d_ws, size_t ws_size,
                              hipStream_t stream) {
    const float* x   = (const float*)d_in[0];
    const int*   ei  = (const int*)d_in[1];   // (2, E): [0,E)=src, [E,2E)=dst
    const float* ew  = (const float*)d_in[2];
    const float* W1  = (const float*)d_in[3];
    const float* b1  = (const float*)d_in[4];
    const float* W2  = (const float*)d_in[5];
    const float* b2  = (const float*)d_in[6];
    const float* Wm1 = (const float*)d_in[7];
    const float* bm1 = (const float*)d_in[8];
    const float* Wm2 = (const float*)d_in[9];
    const float* bm2 = (const float*)d_in[10];
    float* out = (float*)d_out;

    char* base = (char*)d_ws;
    float* dinv = (float*)base;
    float* A    = (float*)(base + 400128);
    float* B    = (float*)(base + 26000128);
    int*   rs    = (int*)(base + 51600128);
    int*   bsum  = (int*)(base + 52000128);
    int*   bpref = (int*)(base + 52000520);
    int2*  pairs = (int2*)(base + 52000912);
    int*   cnt   = (int*)B;  // B dead until aggregate1 writes it

    const int* src = ei;
    const int* dst = ei + NE;

    const bool full = ws_size >= (size_t)64800912;
    const bool douta = !full && ws_size >= (size_t)52000912;
    const int g_node = (NN + 255) / 256;        // 391
    const int g_edge = NE / 256;                // 6250
    const int g_gemm = (NN + 255) / 256;        // 391
    const int g_agg  = (NN + 3) / 4;            // 25000

    if (full || douta) {
        k_zero<<<dim3(g_node), dim3(256), 0, stream>>>(cnt);
        // fused: gemm1 (A = x@W1) + cnt histogram
        k_g1_hist<<<dim3(G1B + HISTB), dim3(256), 0, stream>>>(x, W1, A, dst, cnt);
        // scan cnt -> rs (row starts)
        k_scan1<<<dim3(SCAN_B), dim3(256), 0, stream>>>(cnt, rs, bsum);
        k_scan2<<<dim3(1), dim3(128), 0, stream>>>(bsum, bpref);
        k_scan3<<<dim3(g_node), dim3(256), 0, stream>>>(rs, bpref);
        // fill CSR (rs becomes row ends), then deg/dinv from CSR (no atomics)
        if (full) {
            k_fill_full<<<dim3(g_edge), dim3(256), 0, stream>>>(src, dst, ew, rs, pairs);
            k_degdinv_full<<<dim3(g_node), dim3(256), 0, stream>>>(rs, pairs, dinv);
            k_agg_full<<<dim3(g_agg), dim3(256), 0, stream>>>(rs, pairs, dinv, A, B);
        } else {
            k_fill_eid<<<dim3(g_edge), dim3(256), 0, stream>>>(dst, rs, (int*)d_out);
            k_degdinv_ind<<<dim3(g_node), dim3(256), 0, stream>>>(rs, (int*)d_out, ew, dinv);
            k_agg_ind<<<dim3(g_agg), dim3(256), 0, stream>>>(rs, (int*)d_out, src, ew, dinv, A, B);
        }
        // layer 2
        k_gemm64<false><<<dim3(g_gemm), dim3(256), 0, stream>>>(B, b1, W2, nullptr, A);
        if (full)
            k_agg_full<<<dim3(g_agg), dim3(256), 0, stream>>>(rs, pairs, dinv, A, B);
        else
            k_agg_ind<<<dim3(g_agg), dim3(256), 0, stream>>>(rs, (int*)d_out, src, ew, dinv, A, B);
        // MLP head + softmax
        k_gemm64<true><<<dim3(g_gemm), dim3(256), 0, stream>>>(B, b2, Wm1, bm1, A);
        k_out<<<dim3((NN + 1023) / 1024), dim3(256), 0, stream>>>(A, Wm2, bm2, out);
    } else {
        // fallback: atomic scatter
        k_init_fb<<<dim3(g_node), dim3(256), 0, stream>>>(dinv);
        k_edge_fb<<<dim3(g_edge), dim3(256), 0, stream>>>(dst, ew, dinv);
        k_dinv_fb<<<dim3(g_node), dim3(256), 0, stream>>>(dinv);
        k_gemm1<<<dim3(g_gemm), dim3(256), 0, stream>>>(x, W1, A);
        k_selfloop<<<dim3((NN * (HD / 4) + 255) / 256), dim3(256), 0, stream>>>(A, dinv, B);
        k_scatter<<<dim3(NE / 4), dim3(256), 0, stream>>>(src, dst, ew, dinv, A, B);
        k_gemm64<false><<<dim3(g_gemm), dim3(256), 0, stream>>>(B, b1, W2, nullptr, A);
        k_selfloop<<<dim3((NN * (HD / 4) + 255) / 256), dim3(256), 0, stream>>>(A, dinv, B);
        k_scatter<<<dim3(NE / 4), dim3(256), 0, stream>>>(src, dst, ew, dinv, A, B);
        k_gemm64<true><<<dim3(g_gemm), dim3(256), 0, stream>>>(B, b2, Wm1, bm1, A);
        k_out<<<dim3((NN + 1023) / 1024), dim3(256), 0, stream>>>(A, Wm2, bm2, out);
    }
}